// Round 5
// baseline (117.021 us; speedup 1.0000x reference)
//
#include <hip/hip_runtime.h>
#include <hip/hip_bf16.h>
#include <stdint.h>

#define E_  1024
#define H_  16
#define D_  64
#define K_  8
#define B_  4
#define S_  2048
#define KH_ 128   // K_*H_

typedef __attribute__((ext_vector_type(8))) short   short8;
typedef __attribute__((ext_vector_type(8))) ushort  ushort8;
typedef __attribute__((ext_vector_type(4))) float   f32x4;

__device__ __forceinline__ ushort f2bf(float x){
  union { float f; uint32_t u; } v; v.f = x;
  return (ushort)((v.u + 0x7FFFu + ((v.u >> 16) & 1u)) >> 16);
}

// ---------------- K1: qs[k,f] = (queries[k,:]·Wq[k,f,:] + bq)*0.125 -------
__global__ __launch_bounds__(256) void k1_qs(const float* __restrict__ queries,
                                             const float* __restrict__ Wq,
                                             const float* __restrict__ bq,
                                             float* __restrict__ qs){
  int gw = (blockIdx.x * 256 + threadIdx.x) >> 6;
  int lane = threadIdx.x & 63;
  int k = gw >> 10, f = gw & 1023;
  const float* wrow = Wq + ((size_t)(k*E_) + f)*E_;
  const float* qrow = queries + k*E_;
  float acc = 0.f;
  #pragma unroll
  for (int j = 0; j < 4; j++){
    int e = (j*64 + lane)*4;
    float4 w = *(const float4*)(wrow + e);
    float4 q = *(const float4*)(qrow + e);
    acc += w.x*q.x + w.y*q.y + w.z*q.z + w.w*q.w;
  }
  #pragma unroll
  for (int off = 32; off; off >>= 1) acc += __shfl_down(acc, off);
  if (lane == 0) qs[k*E_ + f] = (acc + bq[k*E_ + f]) * 0.125f;
}

// ---------------- K2: qk[k,h,e] (bf16) and qb[k,h] ------------------------
__global__ __launch_bounds__(256) void k2_qk(const float* __restrict__ qs,
                                             const float* __restrict__ Wk,
                                             const float* __restrict__ bk,
                                             ushort* __restrict__ qkb,
                                             float* __restrict__ qb){
  int bid = blockIdx.x;
  int eq = bid & 3;
  int kh = bid >> 2;
  int k = kh >> 4, h = kh & 15;
  __shared__ float qsh[64];
  int t = threadIdx.x;
  if (t < 64) qsh[t] = qs[k*E_ + h*64 + t];
  __syncthreads();
  int e = eq*256 + t;
  const float* wbase = Wk + ((size_t)(k*E_) + h*64)*E_ + e;
  float a = 0.f;
  #pragma unroll 8
  for (int d = 0; d < 64; d++) a += qsh[d] * wbase[(size_t)d*E_];
  qkb[kh*E_ + e] = f2bf(a);
  if (eq == 0 && t == 0){
    float s = 0.f;
    for (int d = 0; d < 64; d++) s += qsh[d] * bk[k*E_ + h*64 + d];
    qb[kh] = s;
  }
}

// ---------------- K3: scores[b,kh,s] = rep·qk + qb + mask (direct-frag) ---
// 512 blocks = b(4) x st(128 s-tiles of 16). 512 thr = 8 waves.
// No LDS, no barriers. Each wave: m-tile = the block's s-16 (shared via L1),
// n-tile = kh wv*16. Batched independent loads (12/lane in flight).
__global__ __launch_bounds__(512) void k3_scores(const float* __restrict__ rep,
                                                 const ushort* __restrict__ qkb,
                                                 const float* __restrict__ qb,
                                                 const float* __restrict__ mask,
                                                 float* __restrict__ scores){
  int bid = blockIdx.x;
  int st = bid & 127;
  int b  = bid >> 7;
  int t = threadIdx.x, wv = t >> 6, lane = t & 63;
  int l0 = lane & 15, l1 = lane >> 4;
  const float*  Arow = rep + ((size_t)(b*S_) + st*16 + l0)*E_;
  const ushort* Brow = qkb + ((size_t)(wv*16) + l0)*E_;
  f32x4 acc = (f32x4){0.f,0.f,0.f,0.f};
  #pragma unroll 2
  for (int g = 0; g < 8; g++){
    float4 a0[4], a1[4]; short8 bfr[4];
    #pragma unroll
    for (int u = 0; u < 4; u++){
      int kc = (g*4 + u)*32 + l1*8;
      a0[u]  = *(const float4*)(Arow + kc);
      a1[u]  = *(const float4*)(Arow + kc + 4);
      bfr[u] = *(const short8*)(Brow + kc);
    }
    #pragma unroll
    for (int u = 0; u < 4; u++){
      ushort8 ua;
      ua[0]=f2bf(a0[u].x); ua[1]=f2bf(a0[u].y); ua[2]=f2bf(a0[u].z); ua[3]=f2bf(a0[u].w);
      ua[4]=f2bf(a1[u].x); ua[5]=f2bf(a1[u].y); ua[6]=f2bf(a1[u].z); ua[7]=f2bf(a1[u].w);
      acc = __builtin_amdgcn_mfma_f32_16x16x32_bf16((short8)ua, bfr[u], acc, 0,0,0);
    }
  }
  // epilogue: D col=lane&15 -> kh_local, row=(lane>>4)*4+r -> s_local
  int kh = wv*16 + l0;
  float qbv = qb[kh];
  int s0 = st*16 + l1*4;
  float4 m = *(const float4*)(mask + b*S_ + s0);
  float4 o;
  o.x = acc[0] + qbv + m.x;
  o.y = acc[1] + qbv + m.y;
  o.z = acc[2] + qbv + m.z;
  o.w = acc[3] + qbv + m.w;
  *(float4*)(scores + ((size_t)(b*KH_) + kh)*S_ + s0) = o;
}

// ---------------- K4: row softmax -> probs bf16 ---------------------------
__global__ __launch_bounds__(256) void k4_softmax(const float* __restrict__ scores,
                                                  ushort* __restrict__ probs){
  __shared__ float red[4];
  int row = blockIdx.x;
  int t = threadIdx.x, wv = t >> 6, lane = t & 63;
  const float* x = scores + (size_t)row * S_;
  float v[8];
  *(float4*)(v)   = *(const float4*)(x + t*8);
  *(float4*)(v+4) = *(const float4*)(x + t*8 + 4);
  float m = v[0];
  #pragma unroll
  for (int i = 1; i < 8; i++) m = fmaxf(m, v[i]);
  #pragma unroll
  for (int off = 32; off; off >>= 1) m = fmaxf(m, __shfl_down(m, off));
  if (lane == 0) red[wv] = m;
  __syncthreads();
  float M = fmaxf(fmaxf(red[0], red[1]), fmaxf(red[2], red[3]));
  __syncthreads();
  float s = 0.f;
  #pragma unroll
  for (int i = 0; i < 8; i++){ v[i] = __expf(v[i] - M); s += v[i]; }
  #pragma unroll
  for (int off = 32; off; off >>= 1) s += __shfl_down(s, off);
  if (lane == 0) red[wv] = s;
  __syncthreads();
  float inv = 1.0f / (red[0] + red[1] + red[2] + red[3]);
  ushort8 o;
  #pragma unroll
  for (int i = 0; i < 8; i++) o[i] = f2bf(v[i] * inv);
  *(ushort8*)(probs + (size_t)row*S_ + t*8) = o;
}

// ---------------- K5: wrepP[sp][b,kh,e] = probs·rep (direct-frag) ---------
// 256 blocks: ep=bid&15 (e-64), b=(bid>>4)&3, sp=bid>>6 (s-512). 8 waves.
// Wave w: e-tile (w&3)*16, kh-half (w>>2)*64 -> 4 m-tiles. No LDS/barriers.
// B-frag from rep f32 per-lane scalar loads (4 rows x 64B lines per instr).
__global__ __launch_bounds__(512) void k5_wrep(const ushort* __restrict__ probs,
                                               const float* __restrict__ rep,
                                               float* __restrict__ wrepP){
  int bid = blockIdx.x;
  int ep = bid & 15, b = (bid >> 4) & 3, sp = bid >> 6;
  int t = threadIdx.x, w = t >> 6, lane = t & 63;
  int l0 = lane & 15, l1 = lane >> 4;
  int e0 = ep*64 + (w & 3)*16;
  int khh = (w >> 2) * 64;
  int s0 = sp * 512;
  const ushort* Ab = probs + ((size_t)(b*KH_) + khh)*S_ + s0;
  const float*  Bb = rep + ((size_t)(b*S_) + s0)*E_ + e0 + l0;
  f32x4 acc[4];
  #pragma unroll
  for (int mt = 0; mt < 4; mt++) acc[mt] = (f32x4){0.f,0.f,0.f,0.f};
  #pragma unroll 2
  for (int kc = 0; kc < 16; kc++){
    int sc = kc*32 + l1*8;
    float bv[8];
    #pragma unroll
    for (int j = 0; j < 8; j++) bv[j] = Bb[(size_t)(sc + j)*E_];
    short8 A[4];
    #pragma unroll
    for (int mt = 0; mt < 4; mt++)
      A[mt] = *(const short8*)(Ab + (size_t)(mt*16 + l0)*S_ + sc);
    ushort8 ub;
    #pragma unroll
    for (int j = 0; j < 8; j++) ub[j] = f2bf(bv[j]);
    #pragma unroll
    for (int mt = 0; mt < 4; mt++)
      acc[mt] = __builtin_amdgcn_mfma_f32_16x16x32_bf16(A[mt], (short8)ub, acc[mt], 0,0,0);
  }
  // epilogue: col=lane&15 -> e, row=(lane>>4)*4+r -> kh
  float* op = wrepP + ((size_t)sp*B_ + b)*((size_t)KH_*E_);
  #pragma unroll
  for (int mt = 0; mt < 4; mt++){
    int khbase = khh + mt*16 + l1*4;
    #pragma unroll
    for (int r = 0; r < 4; r++)
      op[(size_t)(khbase + r)*E_ + e0 + l0] = acc[mt][r];
  }
}

// ---------------- K6c: wrep = sum of 4 sp-partials ------------------------
__global__ __launch_bounds__(256) void k6c_comb(const float* __restrict__ wrepP,
                                                float* __restrict__ wrep){
  const size_t P = (size_t)B_*KH_*E_;
  size_t i = ((size_t)blockIdx.x * 256 + threadIdx.x) * 4;
  float4 p0 = *(const float4*)(wrepP + i);
  float4 p1 = *(const float4*)(wrepP + i + P);
  float4 p2 = *(const float4*)(wrepP + i + 2*P);
  float4 p3 = *(const float4*)(wrepP + i + 3*P);
  float4 o;
  o.x = (p0.x + p1.x) + (p2.x + p3.x);
  o.y = (p0.y + p1.y) + (p2.y + p3.y);
  o.z = (p0.z + p1.z) + (p2.z + p3.z);
  o.w = (p0.w + p1.w) + (p2.w + p3.w);
  *(float4*)(wrep + i) = o;
}

// ---------------- K6: ctx[k,b,f] = wrep[b,kh(f),:]·Wv[k,f,:] + bv ---------
// gemv-style; x working set per (k,h) = 16 KB -> L1-resident.
__global__ __launch_bounds__(256) void k6_ctx(const float* __restrict__ wrep,
                                              const float* __restrict__ Wv,
                                              const float* __restrict__ bv,
                                              float* __restrict__ ctx){
  int gw = (blockIdx.x*256 + threadIdx.x) >> 6;
  int lane = threadIdx.x & 63;
  int k = gw >> 10, f = gw & 1023;
  int h = f >> 6;
  const float* wrow = Wv + ((size_t)(k*E_) + f)*E_;
  const float* x0 = wrep + ((size_t)(0*KH_) + k*16 + h)*E_;
  const float* x1 = wrep + ((size_t)(1*KH_) + k*16 + h)*E_;
  const float* x2 = wrep + ((size_t)(2*KH_) + k*16 + h)*E_;
  const float* x3 = wrep + ((size_t)(3*KH_) + k*16 + h)*E_;
  float a0=0.f, a1=0.f, a2=0.f, a3=0.f;
  #pragma unroll
  for (int j = 0; j < 4; j++){
    int e = (j*64 + lane)*4;
    float4 w = *(const float4*)(wrow + e);
    float4 p;
    p = *(const float4*)(x0+e); a0 += w.x*p.x + w.y*p.y + w.z*p.z + w.w*p.w;
    p = *(const float4*)(x1+e); a1 += w.x*p.x + w.y*p.y + w.z*p.z + w.w*p.w;
    p = *(const float4*)(x2+e); a2 += w.x*p.x + w.y*p.y + w.z*p.z + w.w*p.w;
    p = *(const float4*)(x3+e); a3 += w.x*p.x + w.y*p.y + w.z*p.z + w.w*p.w;
  }
  #pragma unroll
  for (int off = 32; off; off >>= 1){
    a0 += __shfl_down(a0, off); a1 += __shfl_down(a1, off);
    a2 += __shfl_down(a2, off); a3 += __shfl_down(a3, off);
  }
  if (lane == 0){
    float bvv = bv[k*E_ + f];
    ctx[((size_t)(k*B_) + 0)*E_ + f] = a0 + bvv;
    ctx[((size_t)(k*B_) + 1)*E_ + f] = a1 + bvv;
    ctx[((size_t)(k*B_) + 2)*E_ + f] = a2 + bvv;
    ctx[((size_t)(k*B_) + 3)*E_ + f] = a3 + bvv;
  }
}

// ---------------- K7/K8: out[(k,b),f] = in[(k,b),:]·W[k,f,:] + bias -------
__global__ __launch_bounds__(256) void gemv_kb(const float* __restrict__ in,
                                               const float* __restrict__ W,
                                               const float* __restrict__ bias,
                                               float* __restrict__ outp){
  int gw = (blockIdx.x*256 + threadIdx.x) >> 6;
  int lane = threadIdx.x & 63;
  int k = gw >> 10, f = gw & 1023;
  const float* wrow = W + ((size_t)(k*E_) + f)*E_;
  const float* x0 = in + ((size_t)(k*B_) + 0)*E_;
  const float* x1 = in + ((size_t)(k*B_) + 1)*E_;
  const float* x2 = in + ((size_t)(k*B_) + 2)*E_;
  const float* x3 = in + ((size_t)(k*B_) + 3)*E_;
  float a0=0.f, a1=0.f, a2=0.f, a3=0.f;
  #pragma unroll
  for (int j = 0; j < 4; j++){
    int e = (j*64 + lane)*4;
    float4 w = *(const float4*)(wrow + e);
    float4 p;
    p = *(const float4*)(x0+e); a0 += w.x*p.x + w.y*p.y + w.z*p.z + w.w*p.w;
    p = *(const float4*)(x1+e); a1 += w.x*p.x + w.y*p.y + w.z*p.z + w.w*p.w;
    p = *(const float4*)(x2+e); a2 += w.x*p.x + w.y*p.y + w.z*p.z + w.w*p.w;
    p = *(const float4*)(x3+e); a3 += w.x*p.x + w.y*p.y + w.z*p.z + w.w*p.w;
  }
  #pragma unroll
  for (int off = 32; off; off >>= 1){
    a0 += __shfl_down(a0, off); a1 += __shfl_down(a1, off);
    a2 += __shfl_down(a2, off); a3 += __shfl_down(a3, off);
  }
  if (lane == 0){
    float bb = bias[k*E_ + f];
    outp[((size_t)(k*B_) + 0)*E_ + f] = a0 + bb;
    outp[((size_t)(k*B_) + 1)*E_ + f] = a1 + bb;
    outp[((size_t)(k*B_) + 2)*E_ + f] = a2 + bb;
    outp[((size_t)(k*B_) + 3)*E_ + f] = a3 + bb;
  }
}

// ---------------- K9: LayerNorm over E, write d_out[b,k,e] ----------------
__global__ __launch_bounds__(256) void k9_ln(const float* __restrict__ outkb,
                                             const float* __restrict__ gamma,
                                             const float* __restrict__ beta,
                                             float* __restrict__ out){
  __shared__ float rs[4], rs2[4];
  int row = blockIdx.x;            // b*K_ + k
  int b = row >> 3, k = row & 7;
  int t = threadIdx.x, wv = t >> 6, lane = t & 63;
  const float* x = outkb + ((size_t)(k*B_) + b)*E_;
  float4 v = *(const float4*)(x + t*4);
  float s  = v.x + v.y + v.z + v.w;
  float s2 = v.x*v.x + v.y*v.y + v.z*v.z + v.w*v.w;
  #pragma unroll
  for (int off = 32; off; off >>= 1){ s += __shfl_down(s, off); s2 += __shfl_down(s2, off); }
  if (lane == 0){ rs[wv] = s; rs2[wv] = s2; }
  __syncthreads();
  float S  = rs[0] + rs[1] + rs[2] + rs[3];
  float S2 = rs2[0] + rs2[1] + rs2[2] + rs2[3];
  float mu = S * (1.0f/E_);
  float var = S2 * (1.0f/E_) - mu*mu;
  float inv = rsqrtf(var + 1e-5f);
  float4 g  = *(const float4*)(gamma + t*4);
  float4 bt = *(const float4*)(beta + t*4);
  float4 o;
  o.x = g.x*(v.x-mu)*inv + bt.x;
  o.y = g.y*(v.y-mu)*inv + bt.y;
  o.z = g.z*(v.z-mu)*inv + bt.z;
  o.w = g.w*(v.w-mu)*inv + bt.w;
  *(float4*)(out + ((size_t)(b*K_) + k)*E_ + t*4) = o;
}

extern "C" void kernel_launch(void* const* d_in, const int* in_sizes, int n_in,
                              void* d_out, int out_size, void* d_ws, size_t ws_size,
                              hipStream_t stream){
  const float* rep     = (const float*)d_in[0];
  const float* mask    = (const float*)d_in[1];
  const float* queries = (const float*)d_in[2];
  const float* Wq = (const float*)d_in[3];
  const float* bq = (const float*)d_in[4];
  const float* Wk = (const float*)d_in[5];
  const float* bk = (const float*)d_in[6];
  const float* Wv = (const float*)d_in[7];
  const float* bv = (const float*)d_in[8];
  const float* Wo = (const float*)d_in[9];
  const float* bo = (const float*)d_in[10];
  const float* Wp = (const float*)d_in[11];
  const float* bp = (const float*)d_in[12];
  const float* gamma = (const float*)d_in[13];
  const float* beta  = (const float*)d_in[14];
  float* out = (float*)d_out;

  char* ws = (char*)d_ws;
  size_t off = 0;
  float*  qs    = (float*)(ws + off);  off += (size_t)K_*E_*4;         // 32 KB
  ushort* qkb   = (ushort*)(ws + off); off += (size_t)KH_*E_*2;        // 256 KB
  float*  qb    = (float*)(ws + off);  off += 1024;
  float*  scores= (float*)(ws + off);  off += (size_t)B_*KH_*S_*4;     // 4 MB
  ushort* probs = (ushort*)(ws + off); off += (size_t)B_*KH_*S_*2;     // 2 MB
  float*  wrepP = (float*)(ws + off);  off += (size_t)4*B_*KH_*E_*4;   // 8 MB
  float*  wrep  = (float*)(ws + off);  off += (size_t)B_*KH_*E_*4;     // 2 MB
  float*  ctx   = (float*)(ws + off);  off += (size_t)K_*B_*E_*4;
  float*  attn  = (float*)(ws + off);  off += (size_t)K_*B_*E_*4;
  float*  outkb = (float*)(ws + off);  off += (size_t)K_*B_*E_*4;

  k1_qs     <<<2048, 256, 0, stream>>>(queries, Wq, bq, qs);
  k2_qk     <<<512,  256, 0, stream>>>(qs, Wk, bk, qkb, qb);
  k3_scores <<<512,  512, 0, stream>>>(rep, qkb, qb, mask, scores);
  k4_softmax<<<512,  256, 0, stream>>>(scores, probs);
  k5_wrep   <<<256,  512, 0, stream>>>(probs, rep, wrepP);
  k6c_comb  <<<512,  256, 0, stream>>>(wrepP, wrep);
  k6_ctx    <<<2048, 256, 0, stream>>>(wrep, Wv, bv, ctx);
  gemv_kb   <<<2048, 256, 0, stream>>>(ctx, Wo, bo, attn);
  gemv_kb   <<<2048, 256, 0, stream>>>(attn, Wp, bp, outkb);
  k9_ln     <<<32,   256, 0, stream>>>(outkb, gamma, beta, out);
}

// Round 6
// 80.816 us; speedup vs baseline: 1.4480x; 1.4480x over previous
//
#include <hip/hip_runtime.h>
#include <hip/hip_bf16.h>
#include <stdint.h>

#define E_  1024
#define H_  16
#define D_  64
#define K_  8
#define B_  4
#define S_  2048
#define KH_ 128   // K_*H_

typedef __attribute__((ext_vector_type(8))) short   short8;
typedef __attribute__((ext_vector_type(8))) ushort  ushort8;
typedef __attribute__((ext_vector_type(4))) ushort  ushort4v;
typedef __attribute__((ext_vector_type(4))) float   f32x4;

__device__ __forceinline__ ushort f2bf(float x){
  union { float f; uint32_t u; } v; v.f = x;
  return (ushort)((v.u + 0x7FFFu + ((v.u >> 16) & 1u)) >> 16);
}

// ---------------- K1: qs[k,f] = (queries[k,:]·Wq[k,f,:] + bq)*0.125 -------
__global__ __launch_bounds__(256) void k1_qs(const float* __restrict__ queries,
                                             const float* __restrict__ Wq,
                                             const float* __restrict__ bq,
                                             float* __restrict__ qs){
  int gw = (blockIdx.x * 256 + threadIdx.x) >> 6;
  int lane = threadIdx.x & 63;
  int k = gw >> 10, f = gw & 1023;
  const float* wrow = Wq + ((size_t)(k*E_) + f)*E_;
  const float* qrow = queries + k*E_;
  float acc = 0.f;
  #pragma unroll
  for (int j = 0; j < 4; j++){
    int e = (j*64 + lane)*4;
    float4 w = *(const float4*)(wrow + e);
    float4 q = *(const float4*)(qrow + e);
    acc += w.x*q.x + w.y*q.y + w.z*q.z + w.w*q.w;
  }
  #pragma unroll
  for (int off = 32; off; off >>= 1) acc += __shfl_down(acc, off);
  if (lane == 0) qs[k*E_ + f] = (acc + bq[k*E_ + f]) * 0.125f;
}

// ---------------- K2: qk[k,h,e] (bf16) and qb[k,h] ------------------------
__global__ __launch_bounds__(256) void k2_qk(const float* __restrict__ qs,
                                             const float* __restrict__ Wk,
                                             const float* __restrict__ bk,
                                             ushort* __restrict__ qkb,
                                             float* __restrict__ qb){
  int bid = blockIdx.x;
  int eq = bid & 3;
  int kh = bid >> 2;
  int k = kh >> 4, h = kh & 15;
  __shared__ float qsh[64];
  int t = threadIdx.x;
  if (t < 64) qsh[t] = qs[k*E_ + h*64 + t];
  __syncthreads();
  int e = eq*256 + t;
  const float* wbase = Wk + ((size_t)(k*E_) + h*64)*E_ + e;
  float a = 0.f;
  #pragma unroll 8
  for (int d = 0; d < 64; d++) a += qsh[d] * wbase[(size_t)d*E_];
  qkb[kh*E_ + e] = f2bf(a);
  if (eq == 0 && t == 0){
    float s = 0.f;
    for (int d = 0; d < 64; d++) s += qsh[d] * bk[k*E_ + h*64 + d];
    qb[kh] = s;
  }
}

// ---------------- K3: scoresP[ks][b,kh,s] partial = rep·qk ----------------
// 512 blocks: ks=bid&3 (K-slice 256), m=(bid>>2)&31 (64-s tile), b=bid>>7.
// 256 thr = 4 waves (2x2): wave = 32 s x 64 kh = 2 m-frag x 4 n-frag.
// Reg->cvt->LDS double-buffer, depth-2 prefetch, 8 MFMA per 32-K chunk.
__global__ __launch_bounds__(256) void k3_scores(const float* __restrict__ rep,
                                                 const ushort* __restrict__ qkb,
                                                 float* __restrict__ scoresP){
  __shared__ __align__(16) ushort As[2][64][40];
  __shared__ __align__(16) ushort Bs[2][128][40];
  int bid = blockIdx.x;
  int ks = bid & 3, m = (bid >> 2) & 31, b = bid >> 7;
  int t = threadIdx.x, wv = t >> 6, lane = t & 63;
  int l0 = lane & 15, l1 = lane >> 4;
  int wr = wv >> 1, wc = wv & 1;
  // staging roles
  int arow = t >> 2, acg = t & 3;                 // A: 64 rows x (2 float4)
  int brow = t >> 1, bhalf = t & 1;               // B: 128 rows x (2 ushort8)
  const float*  aSrc = rep + ((size_t)(b*S_) + m*64 + arow)*E_ + ks*256 + acg*4;
  const ushort* bSrc = qkb + (size_t)brow*E_ + ks*256 + bhalf*16;

  f32x4 acc[2][4];
  #pragma unroll
  for (int mt = 0; mt < 2; mt++)
    #pragma unroll
    for (int nt = 0; nt < 4; nt++) acc[mt][nt] = (f32x4){0.f,0.f,0.f,0.f};

  float4  va[2][2];
  ushort8 vb[2][2];
  // issue L0, L1
  #pragma unroll
  for (int p = 0; p < 2; p++){
    va[p][0] = *(const float4*)(aSrc + p*32);
    va[p][1] = *(const float4*)(aSrc + p*32 + 16);
    vb[p][0] = *(const ushort8*)(bSrc + p*32);
    vb[p][1] = *(const ushort8*)(bSrc + p*32 + 8);
  }
  // write chunk0 -> buf0
  #pragma unroll
  for (int j = 0; j < 2; j++){
    ushort4v u;
    u[0]=f2bf(va[0][j].x); u[1]=f2bf(va[0][j].y); u[2]=f2bf(va[0][j].z); u[3]=f2bf(va[0][j].w);
    *(ushort4v*)&As[0][arow][acg*4 + j*16] = u;
    *(ushort8*)&Bs[0][brow][bhalf*16 + j*8] = vb[0][j];
  }
  __syncthreads();

  #pragma unroll
  for (int c = 0; c < 8; c++){
    const int cur = c & 1;
    // compute chunk c
    short8 af[2], bf[4];
    #pragma unroll
    for (int mt = 0; mt < 2; mt++)
      af[mt] = *(const short8*)&As[cur][wr*32 + mt*16 + l0][l1*8];
    #pragma unroll
    for (int nt = 0; nt < 4; nt++)
      bf[nt] = *(const short8*)&Bs[cur][wc*64 + nt*16 + l0][l1*8];
    #pragma unroll
    for (int mt = 0; mt < 2; mt++)
      #pragma unroll
      for (int nt = 0; nt < 4; nt++)
        acc[mt][nt] = __builtin_amdgcn_mfma_f32_16x16x32_bf16(af[mt], bf[nt], acc[mt][nt], 0,0,0);
    // issue loads for chunk c+2
    if (c < 6){
      const int p = c & 1;
      va[p][0] = *(const float4*)(aSrc + (c+2)*32);
      va[p][1] = *(const float4*)(aSrc + (c+2)*32 + 16);
      vb[p][0] = *(const ushort8*)(bSrc + (c+2)*32);
      vb[p][1] = *(const ushort8*)(bSrc + (c+2)*32 + 8);
    }
    // cvt+write chunk c+1 (issued one iter ago) into other buffer
    if (c < 7){
      const int p = (c+1) & 1;
      #pragma unroll
      for (int j = 0; j < 2; j++){
        ushort4v u;
        u[0]=f2bf(va[p][j].x); u[1]=f2bf(va[p][j].y); u[2]=f2bf(va[p][j].z); u[3]=f2bf(va[p][j].w);
        *(ushort4v*)&As[p][arow][acg*4 + j*16] = u;
        *(ushort8*)&Bs[p][brow][bhalf*16 + j*8] = vb[p][j];
      }
    }
    __syncthreads();
  }
  // epilogue: col=l0 -> kh_local, row=(l1*4+r) -> s_local
  float* obase = scoresP + (size_t)ks*((size_t)B_*KH_*S_) + (size_t)(b*KH_)*S_;
  #pragma unroll
  for (int mt = 0; mt < 2; mt++){
    #pragma unroll
    for (int nt = 0; nt < 4; nt++){
      int kh = wc*64 + nt*16 + l0;
      int s  = m*64 + wr*32 + mt*16 + l1*4;
      float* op = obase + (size_t)kh*S_ + s;
      #pragma unroll
      for (int r = 0; r < 4; r++) op[r] = acc[mt][nt][r];
    }
  }
}

// ---------------- K4: softmax over 4 partials + qb + mask -> probs bf16 ---
__global__ __launch_bounds__(256) void k4_softmax(const float* __restrict__ scoresP,
                                                  const float* __restrict__ qb,
                                                  const float* __restrict__ mask,
                                                  ushort* __restrict__ probs){
  __shared__ float red[4];
  const size_t P = (size_t)B_*KH_*S_;
  int row = blockIdx.x;            // b*KH + kh
  int b = row >> 7, kh = row & 127;
  int t = threadIdx.x, wv = t >> 6, lane = t & 63;
  const float* x = scoresP + (size_t)row * S_ + t*8;
  const float* mrow = mask + b*S_ + t*8;
  float qbv = qb[kh];
  float v[8];
  #pragma unroll
  for (int h = 0; h < 2; h++){
    float4 p0 = *(const float4*)(x + h*4);
    float4 p1 = *(const float4*)(x + h*4 + P);
    float4 p2 = *(const float4*)(x + h*4 + 2*P);
    float4 p3 = *(const float4*)(x + h*4 + 3*P);
    float4 mm = *(const float4*)(mrow + h*4);
    v[h*4+0] = (p0.x + p1.x) + (p2.x + p3.x) + qbv + mm.x;
    v[h*4+1] = (p0.y + p1.y) + (p2.y + p3.y) + qbv + mm.y;
    v[h*4+2] = (p0.z + p1.z) + (p2.z + p3.z) + qbv + mm.z;
    v[h*4+3] = (p0.w + p1.w) + (p2.w + p3.w) + qbv + mm.w;
  }
  float m = v[0];
  #pragma unroll
  for (int i = 1; i < 8; i++) m = fmaxf(m, v[i]);
  #pragma unroll
  for (int off = 32; off; off >>= 1) m = fmaxf(m, __shfl_down(m, off));
  if (lane == 0) red[wv] = m;
  __syncthreads();
  float M = fmaxf(fmaxf(red[0], red[1]), fmaxf(red[2], red[3]));
  __syncthreads();
  float s = 0.f;
  #pragma unroll
  for (int i = 0; i < 8; i++){ v[i] = __expf(v[i] - M); s += v[i]; }
  #pragma unroll
  for (int off = 32; off; off >>= 1) s += __shfl_down(s, off);
  if (lane == 0) red[wv] = s;
  __syncthreads();
  float inv = 1.0f / (red[0] + red[1] + red[2] + red[3]);
  ushort8 o;
  #pragma unroll
  for (int i = 0; i < 8; i++) o[i] = f2bf(v[i] * inv);
  *(ushort8*)(probs + (size_t)row*S_ + t*8) = o;
}

// ---------------- K5: wrepP[sp][b,kh,e] = probs·rep -----------------------
// 512 blocks: et=bid&15 (64-e), b=(bid>>4)&3, sp=bid>>6 (256-s slice).
// 256 thr = 4 waves (2x2): wave = 64 kh x 32 e = 4 m-frag x 2 n-frag.
// A (probs) staged b128; B (rep) transposed into LDS [e][s] with s-rotation
// swizzle (rot = (e>>3 & 3)*8) to break bank conflicts. Depth-2 prefetch.
__global__ __launch_bounds__(256) void k5_wrep(const ushort* __restrict__ probs,
                                               const float* __restrict__ rep,
                                               float* __restrict__ wrepP){
  __shared__ __align__(16) ushort As[2][128][40];
  __shared__ __align__(16) ushort Bs[2][64][40];
  int bid = blockIdx.x;
  int et = bid & 15, b = (bid >> 4) & 3, sp = bid >> 6;
  int t = threadIdx.x, wv = t >> 6, lane = t & 63;
  int l0 = lane & 15, l1 = lane >> 4;
  int wr = wv >> 1, wc = wv & 1;
  int arow = t >> 1, ahalf = t & 1;               // A: 128 rows x (2 ushort8)
  int bsrow = t >> 3, beg = t & 7;                // B: 32 s-rows x 8 e
  const ushort* aSrc = probs + (size_t)(b*KH_ + arow)*S_ + sp*256 + ahalf*16;
  const float*  bSrc = rep + ((size_t)(b*S_) + sp*256 + bsrow)*E_ + et*64 + beg*8;

  f32x4 acc[4][2];
  #pragma unroll
  for (int mt = 0; mt < 4; mt++)
    #pragma unroll
    for (int nt = 0; nt < 2; nt++) acc[mt][nt] = (f32x4){0.f,0.f,0.f,0.f};

  ushort8 va[2][2];
  float4  vb[2][2];
  #pragma unroll
  for (int p = 0; p < 2; p++){
    va[p][0] = *(const ushort8*)(aSrc + p*32);
    va[p][1] = *(const ushort8*)(aSrc + p*32 + 8);
    vb[p][0] = *(const float4*)(bSrc + (size_t)(p*32)*E_);
    vb[p][1] = *(const float4*)(bSrc + (size_t)(p*32)*E_ + 4);
  }
  // write chunk0 -> buf0
  {
    *(ushort8*)&As[0][arow][ahalf*16]     = va[0][0];
    *(ushort8*)&As[0][arow][ahalf*16 + 8] = va[0][1];
    int rot = (beg & 3) * 8;
    int sw = (bsrow + rot) & 31;
    #pragma unroll
    for (int j = 0; j < 2; j++){
      float vv[4] = {vb[0][j].x, vb[0][j].y, vb[0][j].z, vb[0][j].w};
      #pragma unroll
      for (int jj = 0; jj < 4; jj++)
        Bs[0][beg*8 + j*4 + jj][sw] = f2bf(vv[jj]);
    }
  }
  __syncthreads();

  #pragma unroll
  for (int c = 0; c < 8; c++){
    const int cur = c & 1;
    short8 af[4], bf[2];
    #pragma unroll
    for (int mt = 0; mt < 4; mt++)
      af[mt] = *(const short8*)&As[cur][wr*64 + mt*16 + l0][l1*8];
    #pragma unroll
    for (int nt = 0; nt < 2; nt++){
      int e_loc = wc*32 + nt*16 + l0;
      int sstart = (l1*8 + ((e_loc >> 3) & 3)*8) & 31;
      bf[nt] = *(const short8*)&Bs[cur][e_loc][sstart];
    }
    #pragma unroll
    for (int mt = 0; mt < 4; mt++)
      #pragma unroll
      for (int nt = 0; nt < 2; nt++)
        acc[mt][nt] = __builtin_amdgcn_mfma_f32_16x16x32_bf16(af[mt], bf[nt], acc[mt][nt], 0,0,0);
    if (c < 6){
      const int p = c & 1;
      va[p][0] = *(const ushort8*)(aSrc + (c+2)*32);
      va[p][1] = *(const ushort8*)(aSrc + (c+2)*32 + 8);
      vb[p][0] = *(const float4*)(bSrc + (size_t)((c+2)*32)*E_);
      vb[p][1] = *(const float4*)(bSrc + (size_t)((c+2)*32)*E_ + 4);
    }
    if (c < 7){
      const int p = (c+1) & 1;
      *(ushort8*)&As[p][arow][ahalf*16]     = va[p][0];
      *(ushort8*)&As[p][arow][ahalf*16 + 8] = va[p][1];
      int rot = (beg & 3) * 8;
      int sw = (bsrow + rot) & 31;
      #pragma unroll
      for (int j = 0; j < 2; j++){
        float vv[4] = {vb[p][j].x, vb[p][j].y, vb[p][j].z, vb[p][j].w};
        #pragma unroll
        for (int jj = 0; jj < 4; jj++)
          Bs[p][beg*8 + j*4 + jj][sw] = f2bf(vv[jj]);
      }
    }
    __syncthreads();
  }
  // epilogue: col=l0 -> e_local, row=(l1*4+r) -> kh_local
  float* obase = wrepP + (size_t)sp*((size_t)B_*KH_*E_) + (size_t)(b*KH_)*E_ + et*64;
  #pragma unroll
  for (int mt = 0; mt < 4; mt++){
    #pragma unroll
    for (int nt = 0; nt < 2; nt++){
      int kh = wr*64 + mt*16 + l1*4;
      int e  = wc*32 + nt*16 + l0;
      #pragma unroll
      for (int r = 0; r < 4; r++)
        obase[(size_t)(kh + r)*E_ + e] = acc[mt][nt][r];
    }
  }
}

// ---------------- K6c: wrep = sum of 8 sp-partials ------------------------
__global__ __launch_bounds__(256) void k6c_comb(const float* __restrict__ wrepP,
                                                float* __restrict__ wrep){
  const size_t P = (size_t)B_*KH_*E_;
  size_t i = ((size_t)blockIdx.x * 256 + threadIdx.x) * 4;
  float4 o = {0.f, 0.f, 0.f, 0.f};
  #pragma unroll
  for (int p = 0; p < 8; p++){
    float4 q = *(const float4*)(wrepP + i + p*P);
    o.x += q.x; o.y += q.y; o.z += q.z; o.w += q.w;
  }
  *(float4*)(wrep + i) = o;
}

// ---------------- K6: ctx[k,b,f] = wrep[b,kh(f),:]·Wv[k,f,:] + bv ---------
__global__ __launch_bounds__(256) void k6_ctx(const float* __restrict__ wrep,
                                              const float* __restrict__ Wv,
                                              const float* __restrict__ bv,
                                              float* __restrict__ ctx){
  int gw = (blockIdx.x*256 + threadIdx.x) >> 6;
  int lane = threadIdx.x & 63;
  int k = gw >> 10, f = gw & 1023;
  int h = f >> 6;
  const float* wrow = Wv + ((size_t)(k*E_) + f)*E_;
  const float* x0 = wrep + ((size_t)(0*KH_) + k*16 + h)*E_;
  const float* x1 = wrep + ((size_t)(1*KH_) + k*16 + h)*E_;
  const float* x2 = wrep + ((size_t)(2*KH_) + k*16 + h)*E_;
  const float* x3 = wrep + ((size_t)(3*KH_) + k*16 + h)*E_;
  float a0=0.f, a1=0.f, a2=0.f, a3=0.f;
  #pragma unroll
  for (int j = 0; j < 4; j++){
    int e = (j*64 + lane)*4;
    float4 w = *(const float4*)(wrow + e);
    float4 p;
    p = *(const float4*)(x0+e); a0 += w.x*p.x + w.y*p.y + w.z*p.z + w.w*p.w;
    p = *(const float4*)(x1+e); a1 += w.x*p.x + w.y*p.y + w.z*p.z + w.w*p.w;
    p = *(const float4*)(x2+e); a2 += w.x*p.x + w.y*p.y + w.z*p.z + w.w*p.w;
    p = *(const float4*)(x3+e); a3 += w.x*p.x + w.y*p.y + w.z*p.z + w.w*p.w;
  }
  #pragma unroll
  for (int off = 32; off; off >>= 1){
    a0 += __shfl_down(a0, off); a1 += __shfl_down(a1, off);
    a2 += __shfl_down(a2, off); a3 += __shfl_down(a3, off);
  }
  if (lane == 0){
    float bvv = bv[k*E_ + f];
    ctx[((size_t)(k*B_) + 0)*E_ + f] = a0 + bvv;
    ctx[((size_t)(k*B_) + 1)*E_ + f] = a1 + bvv;
    ctx[((size_t)(k*B_) + 2)*E_ + f] = a2 + bvv;
    ctx[((size_t)(k*B_) + 3)*E_ + f] = a3 + bvv;
  }
}

// ---------------- K7/K8: out[(k,b),f] = in[(k,b),:]·W[k,f,:] + bias -------
__global__ __launch_bounds__(256) void gemv_kb(const float* __restrict__ in,
                                               const float* __restrict__ W,
                                               const float* __restrict__ bias,
                                               float* __restrict__ outp){
  int gw = (blockIdx.x*256 + threadIdx.x) >> 6;
  int lane = threadIdx.x & 63;
  int k = gw >> 10, f = gw & 1023;
  const float* wrow = W + ((size_t)(k*E_) + f)*E_;
  const float* x0 = in + ((size_t)(k*B_) + 0)*E_;
  const float* x1 = in + ((size_t)(k*B_) + 1)*E_;
  const float* x2 = in + ((size_t)(k*B_) + 2)*E_;
  const float* x3 = in + ((size_t)(k*B_) + 3)*E_;
  float a0=0.f, a1=0.f, a2=0.f, a3=0.f;
  #pragma unroll
  for (int j = 0; j < 4; j++){
    int e = (j*64 + lane)*4;
    float4 w = *(const float4*)(wrow + e);
    float4 p;
    p = *(const float4*)(x0+e); a0 += w.x*p.x + w.y*p.y + w.z*p.z + w.w*p.w;
    p = *(const float4*)(x1+e); a1 += w.x*p.x + w.y*p.y + w.z*p.z + w.w*p.w;
    p = *(const float4*)(x2+e); a2 += w.x*p.x + w.y*p.y + w.z*p.z + w.w*p.w;
    p = *(const float4*)(x3+e); a3 += w.x*p.x + w.y*p.y + w.z*p.z + w.w*p.w;
  }
  #pragma unroll
  for (int off = 32; off; off >>= 1){
    a0 += __shfl_down(a0, off); a1 += __shfl_down(a1, off);
    a2 += __shfl_down(a2, off); a3 += __shfl_down(a3, off);
  }
  if (lane == 0){
    float bb = bias[k*E_ + f];
    outp[((size_t)(k*B_) + 0)*E_ + f] = a0 + bb;
    outp[((size_t)(k*B_) + 1)*E_ + f] = a1 + bb;
    outp[((size_t)(k*B_) + 2)*E_ + f] = a2 + bb;
    outp[((size_t)(k*B_) + 3)*E_ + f] = a3 + bb;
  }
}

// ---------------- K9: LayerNorm over E, write d_out[b,k,e] ----------------
__global__ __launch_bounds__(256) void k9_ln(const float* __restrict__ outkb,
                                             const float* __restrict__ gamma,
                                             const float* __restrict__ beta,
                                             float* __restrict__ out){
  __shared__ float rs[4], rs2[4];
  int row = blockIdx.x;            // b*K_ + k
  int b = row >> 3, k = row & 7;
  int t = threadIdx.x, wv = t >> 6, lane = t & 63;
  const float* x = outkb + ((size_t)(k*B_) + b)*E_;
  float4 v = *(const float4*)(x + t*4);
  float s  = v.x + v.y + v.z + v.w;
  float s2 = v.x*v.x + v.y*v.y + v.z*v.z + v.w*v.w;
  #pragma unroll
  for (int off = 32; off; off >>= 1){ s += __shfl_down(s, off); s2 += __shfl_down(s2, off); }
  if (lane == 0){ rs[wv] = s; rs2[wv] = s2; }
  __syncthreads();
  float S  = rs[0] + rs[1] + rs[2] + rs[3];
  float S2 = rs2[0] + rs2[1] + rs2[2] + rs2[3];
  float mu = S * (1.0f/E_);
  float var = S2 * (1.0f/E_) - mu*mu;
  float inv = rsqrtf(var + 1e-5f);
  float4 g  = *(const float4*)(gamma + t*4);
  float4 bt = *(const float4*)(beta + t*4);
  float4 o;
  o.x = g.x*(v.x-mu)*inv + bt.x;
  o.y = g.y*(v.y-mu)*inv + bt.y;
  o.z = g.z*(v.z-mu)*inv + bt.z;
  o.w = g.w*(v.w-mu)*inv + bt.w;
  *(float4*)(out + ((size_t)(b*K_) + k)*E_ + t*4) = o;
}

extern "C" void kernel_launch(void* const* d_in, const int* in_sizes, int n_in,
                              void* d_out, int out_size, void* d_ws, size_t ws_size,
                              hipStream_t stream){
  const float* rep     = (const float*)d_in[0];
  const float* mask    = (const float*)d_in[1];
  const float* queries = (const float*)d_in[2];
  const float* Wq = (const float*)d_in[3];
  const float* bq = (const float*)d_in[4];
  const float* Wk = (const float*)d_in[5];
  const float* bk = (const float*)d_in[6];
  const float* Wv = (const float*)d_in[7];
  const float* bv = (const float*)d_in[8];
  const float* Wo = (const float*)d_in[9];
  const float* bo = (const float*)d_in[10];
  const float* Wp = (const float*)d_in[11];
  const float* bp = (const float*)d_in[12];
  const float* gamma = (const float*)d_in[13];
  const float* beta  = (const float*)d_in[14];
  float* out = (float*)d_out;

  char* ws = (char*)d_ws;
  size_t off = 0;
  float*  qs     = (float*)(ws + off);  off += (size_t)K_*E_*4;          // 32 KB
  ushort* qkb    = (ushort*)(ws + off); off += (size_t)KH_*E_*2;         // 256 KB
  float*  qb     = (float*)(ws + off);  off += 1024;
  float*  scoresP= (float*)(ws + off);  off += (size_t)4*B_*KH_*S_*4;    // 16 MB
  ushort* probs  = (ushort*)(ws + off); off += (size_t)B_*KH_*S_*2;      // 2 MB
  float*  wrepP  = (float*)(ws + off);  off += (size_t)8*B_*KH_*E_*4;    // 16 MB
  float*  wrep   = (float*)(ws + off);  off += (size_t)B_*KH_*E_*4;      // 2 MB
  float*  ctx    = (float*)(ws + off);  off += (size_t)K_*B_*E_*4;
  float*  attn   = (float*)(ws + off);  off += (size_t)K_*B_*E_*4;
  float*  outkb  = (float*)(ws + off);  off += (size_t)K_*B_*E_*4;

  k1_qs     <<<2048, 256, 0, stream>>>(queries, Wq, bq, qs);
  k2_qk     <<<512,  256, 0, stream>>>(qs, Wk, bk, qkb, qb);
  k3_scores <<<512,  256, 0, stream>>>(rep, qkb, scoresP);
  k4_softmax<<<512,  256, 0, stream>>>(scoresP, qb, mask, probs);
  k5_wrep   <<<512,  256, 0, stream>>>(probs, rep, wrepP);
  k6c_comb  <<<512,  256, 0, stream>>>(wrepP, wrep);
  k6_ctx    <<<2048, 256, 0, stream>>>(wrep, Wv, bv, ctx);
  gemv_kb   <<<2048, 256, 0, stream>>>(ctx, Wo, bo, attn);
  gemv_kb   <<<2048, 256, 0, stream>>>(attn, Wp, bp, outkb);
  k9_ln     <<<32,   256, 0, stream>>>(outkb, gamma, beta, out);
}